// Round 2
// baseline (84.144 us; speedup 1.0000x reference)
//
#include <hip/hip_runtime.h>
#include <stdint.h>

typedef short bf16x8 __attribute__((ext_vector_type(8)));
typedef float f32x4 __attribute__((ext_vector_type(4)));

__device__ __forceinline__ unsigned short f2bf(float f) {
  unsigned u = __float_as_uint(f);
  u += 0x7fffu + ((u >> 16) & 1u);   // RNE round to bf16
  return (unsigned short)(u >> 16);
}

// ---------------- prep: emb fp32 -> bf16 (ws), half ||e||^2 ----------------
__global__ __launch_bounds__(256) void k_prep(const float* __restrict__ emb,
                                              unsigned short* __restrict__ embb,
                                              float* __restrict__ h2) {
  const int t = threadIdx.x;
  const int n = blockIdx.x * 8 + (t >> 5);
  const int c0 = (t & 31) * 8;
  const float* src = emb + (size_t)n * 256 + c0;
  float s = 0.f;
  union { bf16x8 v; unsigned short u[8]; } pk;
#pragma unroll
  for (int i = 0; i < 8; ++i) {
    float f = src[i];
    s += f * f;
    pk.u[i] = f2bf(f);
  }
  *(bf16x8*)(embb + (size_t)n * 256 + c0) = pk.v;
#pragma unroll
  for (int m = 1; m < 32; m <<= 1) s += __shfl_xor(s, m);
  if ((t & 31) == 0) h2[n] = 0.5f * s;
}

// ---------------- main: 1024 blocks x 32 rows, deferred argmax -------------
__global__ __launch_bounds__(256, 3) void k_main(
    const float* __restrict__ z, const float* __restrict__ emb,
    const unsigned short* __restrict__ embb, const float* __restrict__ h2,
    float* __restrict__ out, float* __restrict__ acc_g) {

  // lB[0] (16KB) doubles as lA (32 rows x 32 swizzled 16B slots) before the loop
  __shared__ __align__(16) unsigned short lB[2][128 * 64];
  __shared__ float candv[4][32];
  __shared__ int   candi[4][32];
  __shared__ float red[4];

  const int t = threadIdx.x;
  const int lane = t & 63;
  const int w = t >> 6;            // wave 0..3 -> owns cols [w*32, w*32+32) of each chunk
  const int l15 = lane & 15;
  const int l4 = lane >> 4;
  const int blk = blockIdx.x;
  const int b = blk >> 5;
  const int hw0 = (blk & 31) * 32;

  unsigned short* lA = &lB[0][0];

  // stage B tile [128 n][64 k] (bn,ks) into lB[buf]; linear LDS dest,
  // swizzle folded into per-lane GLOBAL source address.
  auto stageB = [&](int bn, int ks, int buf) {
    const unsigned short* base = embb + (size_t)(bn * 128) * 256 + ks * 64;
#pragma unroll
    for (int rd = 0; rd < 4; ++rd) {
      const int nl = rd * 32 + (t >> 3);     // emb row 0..127
      const int p  = t & 7;                  // physical 16B slot
      const int kc = (p ^ (nl & 7)) * 8;     // logical k-chunk
      const unsigned short* g = base + (size_t)nl * 256 + kc;
      char* l = (char*)(&lB[buf][0]) + rd * 4096 + w * 1024; // wave-uniform base
      __builtin_amdgcn_global_load_lds((const __attribute__((address_space(1))) void*)g,
                                       (__attribute__((address_space(3))) void*)l,
                                       16, 0, 0);
    }
  };

  stageB(0, 0, 1);   // first B tile -> lB[1] (disjoint from lA) overlaps phase A

  // ---- phase A: z -> lA bf16 (swizzled), sumsq in fp32
  {
    const int q = lane >> 5;                 // 0..1
    const int rr = lane & 31;                // row = hw
    const float* zp = z + (size_t)b * 262144 + hw0 + rr;
    float ss = 0.f;
#pragma unroll
    for (int i = 0; i < 4; ++i) {
      const int chunk = w * 8 + q + 2 * i;   // 0..31 (8-elem c-chunk)
      union { bf16x8 v; unsigned short u[8]; } pk;
#pragma unroll
      for (int j = 0; j < 8; ++j) {
        float f = zp[(size_t)(chunk * 8 + j) * 1024];
        ss += f * f;
        pk.u[j] = f2bf(f);
      }
      const int p = chunk ^ (rr & 7);
      *(bf16x8*)((char*)lA + rr * 512 + p * 16) = pk.v;
    }
#pragma unroll
    for (int m = 1; m < 64; m <<= 1) ss += __shfl_xor(ss, m);
    if (lane == 0) red[w] = ss;
  }
  __syncthreads();   // lA complete; stage0 (buf1) drained too

  // ---- A fragments -> registers (read once), rows mi*16+l15, k chunk ks*8+kk*4+l4
  bf16x8 af0[2][2], af1[2][2], af2[2][2], af3[2][2];   // [kk][mi] per ks
#pragma unroll
  for (int kk = 0; kk < 2; ++kk)
#pragma unroll
    for (int mi = 0; mi < 2; ++mi) {
      const int r = mi * 16 + l15;
      af0[kk][mi] = *(const bf16x8*)((const char*)lA + r * 512 + ((0 * 8 + kk * 4 + l4) ^ (r & 7)) * 16);
      af1[kk][mi] = *(const bf16x8*)((const char*)lA + r * 512 + ((1 * 8 + kk * 4 + l4) ^ (r & 7)) * 16);
      af2[kk][mi] = *(const bf16x8*)((const char*)lA + r * 512 + ((2 * 8 + kk * 4 + l4) ^ (r & 7)) * 16);
      af3[kk][mi] = *(const bf16x8*)((const char*)lA + r * 512 + ((3 * 8 + kk * 4 + l4) ^ (r & 7)) * 16);
    }
  __syncthreads();   // all waves done reading lA before buf0 staging overwrites it

  f32x4 acc[2][2];
  float bv[2][4];
  int   bi[2][4];
#pragma unroll
  for (int mi = 0; mi < 2; ++mi)
#pragma unroll
    for (int j = 0; j < 4; ++j) { bv[mi][j] = -1e30f; bi[mi][j] = 0; }
  float h[2];

  for (int bn = 0; bn < 8; ++bn) {
#pragma unroll
    for (int ks = 0; ks < 4; ++ks) {
      const int cur = (ks ^ 1) & 1;          // read buffer: ks even->1, odd->0
      if (ks == 0) {
#pragma unroll
        for (int mi = 0; mi < 2; ++mi)
#pragma unroll
          for (int ni = 0; ni < 2; ++ni)
#pragma unroll
            for (int q = 0; q < 4; ++q) acc[mi][ni][q] = 0.f;
        h[0] = h2[bn * 128 + w * 32 + l15];
        h[1] = h2[bn * 128 + w * 32 + 16 + l15];
      }
      // prefetch next stage
      if (ks < 3) stageB(bn, ks + 1, ks & 1);
      else if (bn < 7) stageB(bn + 1, 0, 1);

      bf16x8 bfr[2][2];
#pragma unroll
      for (int ni = 0; ni < 2; ++ni) {
        const int n = w * 32 + ni * 16 + l15;
#pragma unroll
        for (int kk = 0; kk < 2; ++kk) {
          const int p = (kk * 4 + l4) ^ (n & 7);
          bfr[ni][kk] = *(const bf16x8*)((const char*)&lB[cur][0] + n * 128 + p * 16);
        }
      }
#pragma unroll
      for (int kk = 0; kk < 2; ++kk)
#pragma unroll
        for (int mi = 0; mi < 2; ++mi)
#pragma unroll
          for (int ni = 0; ni < 2; ++ni) {
            const bf16x8 a = (ks == 0) ? af0[kk][mi] : (ks == 1) ? af1[kk][mi]
                           : (ks == 2) ? af2[kk][mi] : af3[kk][mi];
            acc[mi][ni] = __builtin_amdgcn_mfma_f32_16x16x32_bf16(a, bfr[ni][kk], acc[mi][ni], 0, 0, 0);
          }

      if (ks == 3) {   // fold this 128-col chunk into per-lane running best (VALU only)
#pragma unroll
        for (int mi = 0; mi < 2; ++mi)
#pragma unroll
          for (int j = 0; j < 4; ++j)
#pragma unroll
            for (int ni = 0; ni < 2; ++ni) {
              const float v = acc[mi][ni][j] - h[ni];
              const int ci = bn * 128 + w * 32 + ni * 16 + l15;
              const int cin = ci + ni * 16;
              if (v > bv[mi][j] || (v == bv[mi][j] && cin < bi[mi][j])) { bv[mi][j] = v; bi[mi][j] = cin; }
            }
      }
      __syncthreads();
    }
  }

  // ---- final argmax reduce: over l15 group, then across waves via LDS
#pragma unroll
  for (int mi = 0; mi < 2; ++mi)
#pragma unroll
    for (int j = 0; j < 4; ++j) {
      float v = bv[mi][j];
      int ci = bi[mi][j];
#pragma unroll
      for (int m = 1; m < 16; m <<= 1) {
        const float ov = __shfl_xor(v, m);
        const int oi = __shfl_xor(ci, m);
        if (ov > v || (ov == v && oi < ci)) { v = ov; ci = oi; }
      }
      if (l15 == 0) {
        const int row = mi * 16 + l4 * 4 + j;
        candv[w][row] = v;
        candi[w][row] = ci;
      }
    }
  __syncthreads();
  if (t < 32) {
    float v = candv[0][t];
    int ci = candi[0][t];
#pragma unroll
    for (int ww = 1; ww < 4; ++ww) {
      const float ov = candv[ww][t];
      const int oi = candi[ww][t];
      if (ov > v || (ov == v && oi < ci)) { v = ov; ci = oi; }
    }
    candv[0][t] = v;
    candi[0][t] = ci;
  }
  __syncthreads();

  // ---- loss partial: sum(z^2) - 2*sum(best score)
  if (w == 0) {
    float tv = (lane < 32) ? candv[0][lane] : 0.f;
#pragma unroll
    for (int m = 1; m < 64; m <<= 1) tv += __shfl_xor(tv, m);
    if (lane == 0) atomicAdd(acc_g, red[0] + red[1] + red[2] + red[3] - 2.f * tv);
  }

  // ---- gather emb fp32 rows, write quantized [B,C,H,W] coalesced over hw
  const int row = t & 31;
  const int g = t >> 5;                      // 0..7
  const int idx = candi[0][row];
  const float* ep = emb + (size_t)idx * 256;
  float* op = out + (size_t)b * 262144 + hw0 + row;
#pragma unroll
  for (int rd = 0; rd < 8; ++rd) {
    const int cb = g * 4 + rd * 32;
    const float4 vv = *(const float4*)(ep + cb);
    op[(size_t)(cb + 0) * 1024] = vv.x;
    op[(size_t)(cb + 1) * 1024] = vv.y;
    op[(size_t)(cb + 2) * 1024] = vv.z;
    op[(size_t)(cb + 3) * 1024] = vv.w;
  }
}

// ---------------- finalize loss ----------------
__global__ void k_fin(const float* __restrict__ acc_g, float* __restrict__ lossp) {
  if (threadIdx.x == 0) lossp[0] = 1.25f * acc_g[0] * (1.0f / 8388608.0f);
}

extern "C" void kernel_launch(void* const* d_in, const int* in_sizes, int n_in,
                              void* d_out, int out_size, void* d_ws, size_t ws_size,
                              hipStream_t stream) {
  (void)in_sizes; (void)n_in; (void)ws_size;
  const float* z   = (const float*)d_in[0];
  const float* emb = (const float*)d_in[1];
  float* out = (float*)d_out;
  char*  ws  = (char*)d_ws;
  unsigned short* embb = (unsigned short*)ws;          // 524288 B
  float* h2  = (float*)(ws + 524288);                  // 4096 B
  float* acc = (float*)(ws + 524288 + 4096);           // 4 B

  hipMemsetAsync(acc, 0, 4, stream);
  hipLaunchKernelGGL(k_prep, dim3(128), dim3(256), 0, stream, emb, embb, h2);
  hipLaunchKernelGGL(k_main, dim3(1024), dim3(256), 0, stream, z, emb, embb, h2, out, acc);
  hipLaunchKernelGGL(k_fin, dim3(1), dim3(64), 0, stream, acc, out + (size_t)out_size - 1);
}